// Round 6
// baseline (1865.696 us; speedup 1.0000x reference)
//
#include <hip/hip_runtime.h>
#include <hip/hip_fp16.h>

// Wavefront-pipelined 20-layer ReLU RNN for MI355X — round 6.
// Round-5 crashed (core dump; suspects: 109KB LDS, manual-vmcnt + spills,
// marginal R=4 liveness). Round 6 keeps ONLY the superstep idea (S=4 steps
// per 32KB ring slot => all global comm events amortized 4x — round-4 lesson:
// per-step polls/publish round trips ~5100cy dominated) and reverts all risky
// mechanisms:
//  - plain __syncthreads() everywhere (rounds 3 vs 4: barrier drains are
//    neutral); publishes right after a full-drain barrier => trivially safe.
//  - __hip_atomic_load/store (relaxed, agent) for all ring traffic — compiler
//    inserts exact waits; robust against spills. No inline asm.
//  - single-buffered bufX (slot staged in LDS) + one inner barrier at j3
//    before unscramble; LDS total 50,688 B (< 64KB known-safe line).
//  - pf of slot s+1 issued at j1 into registers, consumed at j3 (latency
//    hidden under ~2 compute steps).
//  - skew demand 3 supersteps < backpressure cap R (4/8/16 by ws_size).

#define B_    128
#define T_    784
#define H_    256
#define L_    20
#define C_    10
#define G_    8      // batch slices
#define BM_   16     // batch rows per block
#define S_    4      // timesteps per superstep / ring slot
#define NS_   196    // T_/S_
#define SW_   264    // LDS row stride in halves (256 + 8; 16B-aligned rows)
#define RQWS_ 4096   // u64 words per ring slot (4 x 16 x 256 halves = 32KB)

typedef _Float16 v8h __attribute__((ext_vector_type(8)));
typedef float    v4f __attribute__((ext_vector_type(4)));
typedef unsigned long long u64;

union U64H { u64 u; _Float16 h[4]; };

__global__ __launch_bounds__(256, 1)
void rnn_wavefront(const float* __restrict__ x,
                   const float* __restrict__ W_ih0,
                   const float* __restrict__ b_ih0,
                   const float* __restrict__ W_ih,
                   const float* __restrict__ b_ih,
                   const float* __restrict__ W_hh,
                   const float* __restrict__ b_hh,
                   const float* __restrict__ W_fc,
                   const float* __restrict__ b_fc,
                   float* __restrict__ out,
                   unsigned* __restrict__ prod,    // [L_][G_] supersteps complete
                   unsigned* __restrict__ cons,    // [L_][G_] supersteps consumed
                   u64* __restrict__ ring,         // [L_][G_][R][RQWS_]
                   int rmask)                      // R-1, R power of two
{
    const int l    = blockIdx.x >> 3;
    const int g    = blockIdx.x & 7;
    const int tid  = threadIdx.x;
    const int lane = tid & 63;
    const int wave = tid >> 6;
    const int quad = lane >> 4;
    const int s16  = lane & 15;
    const int nbase = wave * 64;   // each wave owns 64 output columns

    __shared__ __align__(16) _Float16 bufX[S_][BM_][SW_];  // staged input slot
    __shared__ __align__(16) _Float16 lH[2][BM_][SW_];     // own h, ping-pong

    // h0 = 0 (both parities). bufX needs no init (l==0 never reads it;
    // l>0 prologue fully overwrites it).
    for (int i = tid; i < 2 * BM_ * SW_; i += 256) (&lH[0][0][0])[i] = (_Float16)0.f;

    // ---- weight B-fragments: lane holds B[k=quad*8+i][n=lane&15] ----
    v8h wf[16][4];
#pragma unroll
    for (int kt = 0; kt < 16; ++kt) {
        const int k0 = kt * 32 + quad * 8;
#pragma unroll
        for (int nt = 0; nt < 4; ++nt) {
            const int j = nbase + nt * 16 + s16;
            v8h w;
            if (kt < 8) {
                if (l == 0) {
#pragma unroll
                    for (int i = 0; i < 8; ++i) w[i] = (_Float16)0.f;
                } else {
                    const float* src = &W_ih[(((size_t)(l - 1) * H_) + j) * H_ + k0];
#pragma unroll
                    for (int i = 0; i < 8; ++i) w[i] = (_Float16)src[i];
                }
            } else {
                const float* src = &W_hh[(((size_t)l * H_) + j) * H_ + (k0 - 256)];
#pragma unroll
                for (int i = 0; i < 8; ++i) w[i] = (_Float16)src[i];
            }
            wf[kt][nt] = w;
        }
    }

    float bias[4], w0v[4];
#pragma unroll
    for (int nt = 0; nt < 4; ++nt) {
        const int j = nbase + nt * 16 + s16;
        bias[nt] = b_hh[l * H_ + j] + ((l == 0) ? b_ih0[j] : b_ih[(l - 1) * H_ + j]);
        w0v[nt]  = (l == 0) ? W_ih0[j] : 0.f;
    }

    unsigned* upprod = prod + ((l > 0 ? l - 1 : 0) * G_ + g);
    unsigned* myprod = prod + (l * G_ + g);
    unsigned* mycons = cons + (l * G_ + g);
    unsigned* dncons = cons + (((l < L_ - 1) ? l + 1 : l) * G_ + g);
    const unsigned R = (unsigned)rmask + 1u;
    u64* myring = ring + ((size_t)(l * G_ + g) * (size_t)R) * RQWS_;
    u64* upring = ring + ((size_t)((l > 0 ? l - 1 : 0) * G_ + g) * (size_t)R) * RQWS_;

    unsigned pSeen = 0, cSeen = 0;   // private to tid64 / tid128

    // ---- prologue (l>0): wait prod>=2 (slot 0 ready + slot 1 for s=0's pf),
    // then stage slot 0 into bufX ----
    if (l > 0) {
        if (tid == 64) {
            while (pSeen < 2u) {
                pSeen = __hip_atomic_load(upprod, __ATOMIC_RELAXED,
                                          __HIP_MEMORY_SCOPE_AGENT);
                if (pSeen < 2u) __builtin_amdgcn_s_sleep(2);
            }
        }
        __syncthreads();   // broadcast the guarantee
#pragma unroll
        for (int jj = 0; jj < S_; ++jj) {
#pragma unroll
            for (int c = 0; c < 4; ++c) {
                U64H v;
                v.u = __hip_atomic_load(upring + ((size_t)jj * 256 + tid) * 4 + c,
                                        __ATOMIC_RELAXED, __HIP_MEMORY_SCOPE_AGENT);
#pragma unroll
                for (int r = 0; r < 4; ++r) bufX[jj][c * 4 + r][tid] = v.h[r];
            }
        }
    }

    for (int s = 0; s < NS_; ++s) {
        const bool pfOK = (l > 0) && (s + 1 < NS_);
        u64 pf[S_][4];
        u64* const wslot = myring + (size_t)(s & rmask) * RQWS_;
        const u64* const rslot = upring + (size_t)((s + 1) & rmask) * RQWS_;

#pragma unroll
        for (int j = 0; j < S_; ++j) {
            const int t = S_ * s + j;
            // top barrier: drains ALL waves' vmem (stores of superstep s-1
            // complete => publish below is safe); LDS writes visible.
            __syncthreads();

            if (j == 0) {
                if (tid == 0) {
                    if (l < L_ - 1 && s > 0)
                        __hip_atomic_store(myprod, (unsigned)s, __ATOMIC_RELAXED,
                                           __HIP_MEMORY_SCOPE_AGENT); // slots <= s-1 done
                    if (l > 0)
                        __hip_atomic_store(mycons, (unsigned)(s + 1), __ATOMIC_RELAXED,
                                           __HIP_MEMORY_SCOPE_AGENT); // slot s staged
                }
                if (tid == 64 && l > 0 && s <= NS_ - 3) {   // guards pf at s+1 (slot s+2)
                    const unsigned tgt = (unsigned)(s + 3);
                    while (pSeen < tgt) {
                        pSeen = __hip_atomic_load(upprod, __ATOMIC_RELAXED,
                                                  __HIP_MEMORY_SCOPE_AGENT);
                        if (pSeen < tgt) __builtin_amdgcn_s_sleep(2);
                    }
                }
                if (tid == 128 && l < L_ - 1 && s >= rmask) { // guards stores of s+1
                    const unsigned tgt = (unsigned)(s - rmask + 1);
                    while (cSeen < tgt) {
                        cSeen = __hip_atomic_load(dncons, __ATOMIC_RELAXED,
                                                  __HIP_MEMORY_SCOPE_AGENT);
                        if (cSeen < tgt) __builtin_amdgcn_s_sleep(2);
                    }
                }
            }

            if (j == 1 && pfOK) {   // prefetch slot s+1 -> regs (used at j3)
#pragma unroll
                for (int jj = 0; jj < S_; ++jj)
#pragma unroll
                    for (int c = 0; c < 4; ++c)
                        pf[jj][c] = __hip_atomic_load(
                            rslot + ((size_t)jj * 256 + tid) * 4 + c,
                            __ATOMIC_RELAXED, __HIP_MEMORY_SCOPE_AGENT);
            }

            // ---- MFMA: acc = [X(t) | h(t-1)] x W^T ----
            v4f acc[4];
#pragma unroll
            for (int nt = 0; nt < 4; ++nt) acc[nt] = (v4f){0.f, 0.f, 0.f, 0.f};
            if (l > 0) {
#pragma unroll
                for (int kt = 0; kt < 8; ++kt) {
                    v8h a = *(const v8h*)&bufX[j][s16][kt * 32 + quad * 8];
#pragma unroll
                    for (int nt = 0; nt < 4; ++nt)
                        acc[nt] = __builtin_amdgcn_mfma_f32_16x16x32_f16(a, wf[kt][nt], acc[nt], 0, 0, 0);
                }
            }
#pragma unroll
            for (int kt = 8; kt < 16; ++kt) {
                v8h a = *(const v8h*)&lH[t & 1][s16][(kt - 8) * 32 + quad * 8];
#pragma unroll
                for (int nt = 0; nt < 4; ++nt)
                    acc[nt] = __builtin_amdgcn_mfma_f32_16x16x32_f16(a, wf[kt][nt], acc[nt], 0, 0, 0);
            }

            float xv[4];
            if (l == 0) {
#pragma unroll
                for (int r = 0; r < 4; ++r)
                    xv[r] = x[(size_t)(g * BM_ + quad * 4 + r) * T_ + t];
            }

            // ---- epilogue: relu(acc+bias) -> lH[(t+1)&1] + ring stores ----
#pragma unroll
            for (int nt = 0; nt < 4; ++nt) {
                const int n = nbase + nt * 16 + s16;
                U64H pk;
#pragma unroll
                for (int r = 0; r < 4; ++r) {
                    float v = acc[nt][r] + bias[nt];
                    if (l == 0) v += xv[r] * w0v[nt];
                    v = fmaxf(v, 0.f);
                    const _Float16 hv = (_Float16)v;
                    lH[(t + 1) & 1][quad * 4 + r][n] = hv;
                    pk.h[r] = hv;
                }
                if (l < L_ - 1)
                    __hip_atomic_store(&wslot[((size_t)j * 256 + n) * 4 + quad],
                                       pk.u, __ATOMIC_RELAXED,
                                       __HIP_MEMORY_SCOPE_AGENT);
            }

            if (j == S_ - 1) {
                __syncthreads();   // all waves done with bufX reads of this superstep
                if (pfOK) {        // unscramble pf -> bufX (next superstep's input)
#pragma unroll
                    for (int jj = 0; jj < S_; ++jj)
#pragma unroll
                        for (int c = 0; c < 4; ++c) {
                            U64H v;
                            v.u = pf[jj][c];
#pragma unroll
                            for (int r = 0; r < 4; ++r)
                                bufX[jj][c * 4 + r][tid] = v.h[r];
                        }
                }
            }
        }
    }

    // ---- final: publish everything complete ----
    __syncthreads();
    if (tid == 0 && l < L_ - 1)
        __hip_atomic_store(myprod, (unsigned)NS_, __ATOMIC_RELAXED,
                           __HIP_MEMORY_SCOPE_AGENT);

    // ---- final FC (layer 19): h_T in lH[0] (t=783 wrote parity 0) ----
    if (l == L_ - 1 && tid < BM_ * C_) {
        const int bl = tid / C_;
        const int c  = tid % C_;
        float sum = b_fc[c];
        for (int k = 0; k < H_; ++k) sum += (float)lH[0][bl][k] * W_fc[c * H_ + k];
        out[(size_t)(g * BM_ + bl) * C_ + c] = sum;
    }
}

extern "C" void kernel_launch(void* const* d_in, const int* in_sizes, int n_in,
                              void* d_out, int out_size, void* d_ws, size_t ws_size,
                              hipStream_t stream) {
    const float* x     = (const float*)d_in[0];
    const float* W_ih0 = (const float*)d_in[1];
    const float* b_ih0 = (const float*)d_in[2];
    const float* W_ih  = (const float*)d_in[3];
    const float* b_ih  = (const float*)d_in[4];
    const float* W_hh  = (const float*)d_in[5];
    const float* b_hh  = (const float*)d_in[6];
    const float* W_fc  = (const float*)d_in[7];
    const float* b_fc  = (const float*)d_in[8];
    float* out = (float*)d_out;

    const size_t cntBytes = (size_t)L_ * G_ * sizeof(unsigned);   // 640 B each
    unsigned* prod = (unsigned*)d_ws;
    unsigned* cons = (unsigned*)((char*)d_ws + cntBytes);
    u64* ring      = (u64*)((char*)d_ws + 2 * cntBytes);

    // ring slots per link, by available workspace (32 KB per slot per link)
    const size_t slotBytes = (size_t)RQWS_ * 8;                   // 32 KB
    const size_t base = 2 * cntBytes;
    int R = 4;                                                    // 21 MB
    if (ws_size >= base + (size_t)L_ * G_ * 16 * slotBytes) R = 16;      // 84 MB
    else if (ws_size >= base + (size_t)L_ * G_ * 8 * slotBytes) R = 8;   // 42 MB

    hipMemsetAsync(d_ws, 0, 2 * cntBytes, stream);

    rnn_wavefront<<<dim3(L_ * G_), dim3(256), 0, stream>>>(
        x, W_ih0, b_ih0, W_ih, b_ih, W_hh, b_hh, W_fc, b_fc,
        out, prod, cons, ring, R - 1);
}

// Round 7
// 1148.178 us; speedup vs baseline: 1.6249x; 1.6249x over previous
//
#include <hip/hip_runtime.h>
#include <hip/hip_fp16.h>

// Wavefront-pipelined 20-layer ReLU RNN for MI355X — round 7.
// Rounds 3/4/6: step time ~4500cy invariant under sync-structure changes =>
// the body is the floor. Theory: 1 wave/SIMD exposes MFMA latency (MFMA
// blocks its wave; acc chains of 16). Fix: 512 threads = 2 waves/SIMD,
// N-split (wave owns 32 cols, 32 MFMA/step) -> 4 indep streams/SIMD.
// Also: row-major ring slots; producer exports h(t-1) (lag 1 step) via
// ds_read_b64 + coalesced 16B/thread coherent stores; consumer prefetch
// unscramble = pure ds_write_b64 (no extraction). LDS stride 280 halves
// (140 dwords === 12 mod 32) for even bank spread.

#define B_    128
#define T_    784
#define H_    256
#define L_    20
#define C_    10
#define G_    8      // batch slices
#define BM_   16     // batch rows per block
#define S_    4      // timesteps per superstep / ring slot
#define NS_   196    // T_/S_
#define SW_   280    // LDS row stride in halves (140 dwords = 12 mod 32)
#define RQWS_ 4096   // u64 words per ring slot (4 x 16 x 256 halves = 32KB)
#define TPB_  512

typedef _Float16 v8h __attribute__((ext_vector_type(8)));
typedef float    v4f __attribute__((ext_vector_type(4)));
typedef unsigned long long u64;

__global__ __launch_bounds__(TPB_, 1)
void rnn_wavefront(const float* __restrict__ x,
                   const float* __restrict__ W_ih0,
                   const float* __restrict__ b_ih0,
                   const float* __restrict__ W_ih,
                   const float* __restrict__ b_ih,
                   const float* __restrict__ W_hh,
                   const float* __restrict__ b_hh,
                   const float* __restrict__ W_fc,
                   const float* __restrict__ b_fc,
                   float* __restrict__ out,
                   unsigned* __restrict__ prod,    // [L_][G_] supersteps complete
                   unsigned* __restrict__ cons,    // [L_][G_] supersteps consumed
                   u64* __restrict__ ring,         // [L_][G_][R][RQWS_]
                   int rmask)                      // R-1, R power of two
{
    const int l    = blockIdx.x >> 3;
    const int g    = blockIdx.x & 7;
    const int tid  = threadIdx.x;
    const int lane = tid & 63;
    const int wave = tid >> 6;          // 0..7
    const int quad = lane >> 4;
    const int s16  = lane & 15;
    const int nbase = wave * 32;        // each wave owns 32 output columns
    const int m_e  = tid >> 5;          // export/pf row (0..15)
    const int n_e  = (tid & 31) * 8;    // export/pf col base (0..248)

    __shared__ __align__(16) _Float16 bufX[S_][BM_][SW_];  // staged input slot
    __shared__ __align__(16) _Float16 lH[2][BM_][SW_];     // own h, ping-pong

    for (int i = tid; i < 2 * BM_ * SW_; i += TPB_) (&lH[0][0][0])[i] = (_Float16)0.f;

    // ---- weight B-fragments: lane holds B[k=quad*8+i][n=lane&15] ----
    v8h wf[16][2];
#pragma unroll
    for (int kt = 0; kt < 16; ++kt) {
        const int k0 = kt * 32 + quad * 8;
#pragma unroll
        for (int nt = 0; nt < 2; ++nt) {
            const int j = nbase + nt * 16 + s16;
            v8h w;
            if (kt < 8) {
                if (l == 0) {
#pragma unroll
                    for (int i = 0; i < 8; ++i) w[i] = (_Float16)0.f;
                } else {
                    const float* src = &W_ih[(((size_t)(l - 1) * H_) + j) * H_ + k0];
#pragma unroll
                    for (int i = 0; i < 8; ++i) w[i] = (_Float16)src[i];
                }
            } else {
                const float* src = &W_hh[(((size_t)l * H_) + j) * H_ + (k0 - 256)];
#pragma unroll
                for (int i = 0; i < 8; ++i) w[i] = (_Float16)src[i];
            }
            wf[kt][nt] = w;
        }
    }

    float bias[2], w0v[2];
#pragma unroll
    for (int nt = 0; nt < 2; ++nt) {
        const int j = nbase + nt * 16 + s16;
        bias[nt] = b_hh[l * H_ + j] + ((l == 0) ? b_ih0[j] : b_ih[(l - 1) * H_ + j]);
        w0v[nt]  = (l == 0) ? W_ih0[j] : 0.f;
    }

    unsigned* upprod = prod + ((l > 0 ? l - 1 : 0) * G_ + g);
    unsigned* myprod = prod + (l * G_ + g);
    unsigned* mycons = cons + (l * G_ + g);
    unsigned* dncons = cons + (((l < L_ - 1) ? l + 1 : l) * G_ + g);
    const unsigned R = (unsigned)rmask + 1u;
    u64* myring = ring + ((size_t)(l * G_ + g) * (size_t)R) * RQWS_;
    u64* upring = ring + ((size_t)((l > 0 ? l - 1 : 0) * G_ + g) * (size_t)R) * RQWS_;

    unsigned pSeen = 0, cSeen = 0;         // tid64 / tid128 private
    const size_t eidx = (size_t)m_e * 64 + (size_t)(tid & 31) * 2;  // u64 idx in [m][n] slot

    // ---- prologue (l>0): wait prod>=2, stage slot 0 into bufX (row-major) ----
    if (l > 0) {
        if (tid == 64) {
            while (pSeen < 2u) {
                pSeen = __hip_atomic_load(upprod, __ATOMIC_RELAXED,
                                          __HIP_MEMORY_SCOPE_AGENT);
                if (pSeen < 2u) __builtin_amdgcn_s_sleep(2);
            }
        }
        __syncthreads();
#pragma unroll
        for (int jj = 0; jj < S_; ++jj) {
            u64 v0 = __hip_atomic_load(upring + (size_t)jj * 1024 + eidx,
                                       __ATOMIC_RELAXED, __HIP_MEMORY_SCOPE_AGENT);
            u64 v1 = __hip_atomic_load(upring + (size_t)jj * 1024 + eidx + 1,
                                       __ATOMIC_RELAXED, __HIP_MEMORY_SCOPE_AGENT);
            *(u64*)&bufX[jj][m_e][n_e]     = v0;
            *(u64*)&bufX[jj][m_e][n_e + 4] = v1;
        }
    }

    for (int s = 0; s < NS_; ++s) {
        const bool pfOK = (l > 0) && (s + 1 < NS_);
        u64 pfv[S_][2];

#pragma unroll
        for (int j = 0; j < S_; ++j) {
            const int t = S_ * s + j;
            __syncthreads();   // step barrier (also drains vmem per compiler)

            if (j == 0) {
                if (tid == 0 && l > 0)
                    __hip_atomic_store(mycons, (unsigned)(s + 1), __ATOMIC_RELAXED,
                                       __HIP_MEMORY_SCOPE_AGENT); // slot s global free
                if (tid == 64 && pfOK) {            // guards pf of slot s+1 at j1
                    const unsigned tgt = (unsigned)(s + 2);
                    while (pSeen < tgt) {
                        pSeen = __hip_atomic_load(upprod, __ATOMIC_RELAXED,
                                                  __HIP_MEMORY_SCOPE_AGENT);
                        if (pSeen < tgt) __builtin_amdgcn_s_sleep(2);
                    }
                }
                if (tid == 128 && l < L_ - 1 && s >= (int)R) {  // guards exports into slot s
                    const unsigned tgt = (unsigned)(s - (int)R + 1);
                    while (cSeen < tgt) {
                        cSeen = __hip_atomic_load(dncons, __ATOMIC_RELAXED,
                                                  __HIP_MEMORY_SCOPE_AGENT);
                        if (cSeen < tgt) __builtin_amdgcn_s_sleep(2);
                    }
                }
            }

            if (j == 1) {
                if (tid == 0 && l < L_ - 1 && s >= 1)
                    __hip_atomic_store(myprod, (unsigned)s, __ATOMIC_RELAXED,
                                       __HIP_MEMORY_SCOPE_AGENT); // slots 0..s-1 done
                if (pfOK) {   // prefetch slot s+1 -> regs (used at j3)
                    const u64* base = upring + (size_t)((s + 1) & rmask) * RQWS_;
#pragma unroll
                    for (int jj = 0; jj < S_; ++jj) {
                        pfv[jj][0] = __hip_atomic_load(base + (size_t)jj * 1024 + eidx,
                                                       __ATOMIC_RELAXED,
                                                       __HIP_MEMORY_SCOPE_AGENT);
                        pfv[jj][1] = __hip_atomic_load(base + (size_t)jj * 1024 + eidx + 1,
                                                       __ATOMIC_RELAXED,
                                                       __HIP_MEMORY_SCOPE_AGENT);
                    }
                }
            }

            // ---- export h(t-1) (lag 1 step; lH[t&1] holds h(t-1)) ----
            if (l < L_ - 1 && t > 0) {
                u64 e0 = *(const u64*)&lH[t & 1][m_e][n_e];
                u64 e1 = *(const u64*)&lH[t & 1][m_e][n_e + 4];
                u64* d = myring + (size_t)(((t - 1) >> 2) & rmask) * RQWS_
                                + (size_t)((t - 1) & 3) * 1024 + eidx;
                __hip_atomic_store(d,     e0, __ATOMIC_RELAXED, __HIP_MEMORY_SCOPE_AGENT);
                __hip_atomic_store(d + 1, e1, __ATOMIC_RELAXED, __HIP_MEMORY_SCOPE_AGENT);
            }

            // ---- MFMA: acc = [X(t) | h(t-1)] x W^T  (32 MFMA/wave) ----
            v4f acc[2];
            acc[0] = (v4f){0.f, 0.f, 0.f, 0.f};
            acc[1] = (v4f){0.f, 0.f, 0.f, 0.f};
            if (l > 0) {
#pragma unroll
                for (int kt = 0; kt < 8; ++kt) {
                    v8h a = *(const v8h*)&bufX[j][s16][kt * 32 + quad * 8];
                    acc[0] = __builtin_amdgcn_mfma_f32_16x16x32_f16(a, wf[kt][0], acc[0], 0, 0, 0);
                    acc[1] = __builtin_amdgcn_mfma_f32_16x16x32_f16(a, wf[kt][1], acc[1], 0, 0, 0);
                }
            }
#pragma unroll
            for (int kt = 8; kt < 16; ++kt) {
                v8h a = *(const v8h*)&lH[t & 1][s16][(kt - 8) * 32 + quad * 8];
                acc[0] = __builtin_amdgcn_mfma_f32_16x16x32_f16(a, wf[kt][0], acc[0], 0, 0, 0);
                acc[1] = __builtin_amdgcn_mfma_f32_16x16x32_f16(a, wf[kt][1], acc[1], 0, 0, 0);
            }

            float xv[4];
            if (l == 0) {
#pragma unroll
                for (int r = 0; r < 4; ++r)
                    xv[r] = x[(size_t)(g * BM_ + quad * 4 + r) * T_ + t];
            }

            // ---- epilogue: relu(acc+bias) -> lH[(t+1)&1] ----
#pragma unroll
            for (int nt = 0; nt < 2; ++nt) {
                const int n = nbase + nt * 16 + s16;
#pragma unroll
                for (int r = 0; r < 4; ++r) {
                    float v = acc[nt][r] + bias[nt];
                    if (l == 0) v += xv[r] * w0v[nt];
                    v = fmaxf(v, 0.f);
                    lH[(t + 1) & 1][quad * 4 + r][n] = (_Float16)v;
                }
            }

            if (j == S_ - 1) {
                __syncthreads();   // all waves done with bufX of this superstep
                if (pfOK) {        // unscramble: pure ds_write_b64, no extraction
#pragma unroll
                    for (int jj = 0; jj < S_; ++jj) {
                        *(u64*)&bufX[jj][m_e][n_e]     = pfv[jj][0];
                        *(u64*)&bufX[jj][m_e][n_e + 4] = pfv[jj][1];
                    }
                }
            }
        }
    }

    if (l < L_ - 1) {
        // tail: export h(T-1) (in lH[0]: (783+1)&1), drain, publish all done
        u64 e0 = *(const u64*)&lH[0][m_e][n_e];
        u64 e1 = *(const u64*)&lH[0][m_e][n_e + 4];
        u64* d = myring + (size_t)(((T_ - 1) >> 2) & rmask) * RQWS_
                        + (size_t)3 * 1024 + eidx;
        __hip_atomic_store(d,     e0, __ATOMIC_RELAXED, __HIP_MEMORY_SCOPE_AGENT);
        __hip_atomic_store(d + 1, e1, __ATOMIC_RELAXED, __HIP_MEMORY_SCOPE_AGENT);
        __syncthreads();   // drains the exports (vmcnt(0) before s_barrier)
        if (tid == 0)
            __hip_atomic_store(myprod, (unsigned)NS_, __ATOMIC_RELAXED,
                               __HIP_MEMORY_SCOPE_AGENT);
    } else {
        __syncthreads();
        // final FC: out[b] = h_T[b] @ W_fc^T + b_fc; h_T in lH[0]
        if (tid < BM_ * C_) {
            const int bl = tid / C_;
            const int c  = tid % C_;
            float sum = b_fc[c];
            for (int k = 0; k < H_; ++k) sum += (float)lH[0][bl][k] * W_fc[c * H_ + k];
            out[(size_t)(g * BM_ + bl) * C_ + c] = sum;
        }
    }
}

extern "C" void kernel_launch(void* const* d_in, const int* in_sizes, int n_in,
                              void* d_out, int out_size, void* d_ws, size_t ws_size,
                              hipStream_t stream) {
    const float* x     = (const float*)d_in[0];
    const float* W_ih0 = (const float*)d_in[1];
    const float* b_ih0 = (const float*)d_in[2];
    const float* W_ih  = (const float*)d_in[3];
    const float* b_ih  = (const float*)d_in[4];
    const float* W_hh  = (const float*)d_in[5];
    const float* b_hh  = (const float*)d_in[6];
    const float* W_fc  = (const float*)d_in[7];
    const float* b_fc  = (const float*)d_in[8];
    float* out = (float*)d_out;

    const size_t cntBytes = (size_t)L_ * G_ * sizeof(unsigned);   // 640 B each
    unsigned* prod = (unsigned*)d_ws;
    unsigned* cons = (unsigned*)((char*)d_ws + cntBytes);
    u64* ring      = (u64*)((char*)d_ws + 2 * cntBytes);

    // ring slots per link, by available workspace (32 KB per slot per link)
    const size_t slotBytes = (size_t)RQWS_ * 8;                   // 32 KB
    const size_t base = 2 * cntBytes;
    int R = 4;                                                    // 21 MB
    if (ws_size >= base + (size_t)L_ * G_ * 16 * slotBytes) R = 16;      // 84 MB
    else if (ws_size >= base + (size_t)L_ * G_ * 8 * slotBytes) R = 8;   // 42 MB

    hipMemsetAsync(d_ws, 0, 2 * cntBytes, stream);

    rnn_wavefront<<<dim3(L_ * G_), dim3(TPB_), 0, stream>>>(
        x, W_ih0, b_ih0, W_ih, b_ih, W_hh, b_hh, W_fc, b_fc,
        out, prod, cons, ring, R - 1);
}